// Round 6
// baseline (782.846 us; speedup 1.0000x reference)
//
#include <hip/hip_runtime.h>
#include <stdint.h>

typedef unsigned short u16;
typedef __attribute__((ext_vector_type(8))) short bf16x8;
typedef __attribute__((ext_vector_type(4))) float f32x4;

#define MFMA_BF16(a,b,c) __builtin_amdgcn_mfma_f32_16x16x32_bf16((a),(b),(c),0,0,0)

// async global->LDS, 16B per lane; LDS dest = wave-uniform base + lane*16
#define GLOAD_LDS16(g, l) \
  __builtin_amdgcn_global_load_lds((const __attribute__((address_space(1))) void*)(g), \
                                   (__attribute__((address_space(3))) void*)(l), 16, 0, 0)

__device__ inline u16 f2bf(float f) {
  uint32_t u = __builtin_bit_cast(uint32_t, f);
  u = (u + 0x7FFFu + ((u >> 16) & 1u)) >> 16;
  return (u16)u;
}
__device__ inline float bf2f(u16 h) {
  uint32_t u = ((uint32_t)h) << 16;
  return __builtin_bit_cast(float, u);
}

// ---------------- fp32 -> bf16 conversion ----------------
__global__ __launch_bounds__(256) void cvt_kernel(const float* __restrict__ src,
                                                  u16* __restrict__ dst, int n4) {
  int i = blockIdx.x * 256 + threadIdx.x;
  if (i >= n4) return;
  float4 v = reinterpret_cast<const float4*>(src)[i];
  uint2 o;
  o.x = (uint32_t)f2bf(v.x) | ((uint32_t)f2bf(v.y) << 16);
  o.y = (uint32_t)f2bf(v.z) | ((uint32_t)f2bf(v.w) << 16);
  reinterpret_cast<uint2*>(dst)[i] = o;
}

// ---------------- GEMM (m97 structure): C = A * B^T + bias ----------------
// 128x128 tile, BK=64, linear LDS [128][64], global_load_lds width-16 staging.
template<typename OutT>
__global__ __launch_bounds__(256) void gemm_bt(
    const u16* __restrict__ A, const u16* __restrict__ B,
    const float* __restrict__ bias, OutT* __restrict__ C,
    int M, int N, int K)
{
  __shared__ u16 As[128 * 64];
  __shared__ u16 Bs[128 * 64];
  const int bm = blockIdx.y, bn = blockIdx.x;
  const int tid = threadIdx.x;
  const int lane = tid & 63;
  const int wv = tid >> 6;
  const int wm = wv >> 1, wn = wv & 1;  // 2x2 wave grid, each wave 64x64
  const int g = lane >> 4, qn = lane & 15;

  f32x4 acc[4][4];
  #pragma unroll
  for (int i = 0; i < 4; ++i)
    #pragma unroll
    for (int j = 0; j < 4; ++j) acc[i][j] = (f32x4){0.f, 0.f, 0.f, 0.f};

  const u16* Ab = A + (size_t)bm * 128 * K;
  const u16* Bb = B + (size_t)bn * 128 * K;
  const int lr = lane >> 3, lc = lane & 7;   // 8 rows x 8 col-slots per instr

  for (int kt = 0; kt < K; kt += 64) {
    __syncthreads();
    #pragma unroll
    for (int i = 0; i < 4; ++i) {
      int r0 = wv * 32 + i * 8;
      size_t goff = (size_t)(r0 + lr) * K + kt + lc * 8;
      GLOAD_LDS16(Ab + goff, As + r0 * 64);
      GLOAD_LDS16(Bb + goff, Bs + r0 * 64);
    }
    __syncthreads();
    #pragma unroll
    for (int ks = 0; ks < 2; ++ks) {
      bf16x8 af[4], bfr[4];
      #pragma unroll
      for (int mi = 0; mi < 4; ++mi)
        af[mi] = *reinterpret_cast<const bf16x8*>(As + (wm * 64 + mi * 16 + qn) * 64 + g * 8 + ks * 32);
      #pragma unroll
      for (int ni = 0; ni < 4; ++ni)
        bfr[ni] = *reinterpret_cast<const bf16x8*>(Bs + (wn * 64 + ni * 16 + qn) * 64 + g * 8 + ks * 32);
      #pragma unroll
      for (int mi = 0; mi < 4; ++mi)
        #pragma unroll
        for (int ni = 0; ni < 4; ++ni)
          acc[mi][ni] = MFMA_BF16(af[mi], bfr[ni], acc[mi][ni]);
    }
  }
  // epilogue: C/D layout col=lane&15, row=(lane>>4)*4+reg
  #pragma unroll
  for (int ni = 0; ni < 4; ++ni) {
    int col = bn * 128 + wn * 64 + ni * 16 + qn;
    float bs = bias[col];
    #pragma unroll
    for (int mi = 0; mi < 4; ++mi) {
      #pragma unroll
      for (int r = 0; r < 4; ++r) {
        int row = bm * 128 + wm * 64 + mi * 16 + g * 4 + r;
        float v = acc[mi][ni][r] + bs;
        if constexpr (sizeof(OutT) == 2) C[(size_t)row * N + col] = (OutT)f2bf(v);
        else                             C[(size_t)row * N + col] = v;
      }
    }
  }
}

// ---------------- RoPE (in-place on bf16 [tok][heads*64]) ----------------
__global__ __launch_bounds__(256) void rope_kernel(
    u16* __restrict__ T, const float* __restrict__ cosT, const float* __restrict__ sinT,
    int heads8, int n8)
{
  int i = blockIdx.x * 256 + threadIdx.x;
  if (i >= n8) return;
  int tok = i / heads8;
  int r = i - tok * heads8;
  int d0 = (r & 7) * 8;
  int s = tok & 2047;
  uint4 v = reinterpret_cast<uint4*>(T)[i];
  u16* e = reinterpret_cast<u16*>(&v);
  float4 c = *reinterpret_cast<const float4*>(cosT + s * 32 + d0 / 2);
  float4 sn = *reinterpret_cast<const float4*>(sinT + s * 32 + d0 / 2);
  float cc[4] = {c.x, c.y, c.z, c.w}, ss[4] = {sn.x, sn.y, sn.z, sn.w};
  #pragma unroll
  for (int j = 0; j < 4; ++j) {
    float tr = bf2f(e[2 * j]), ti = bf2f(e[2 * j + 1]);
    e[2 * j]     = f2bf(tr * cc[j] - ti * ss[j]);
    e[2 * j + 1] = f2bf(tr * ss[j] + ti * cc[j]);
  }
  reinterpret_cast<uint4*>(T)[i] = v;
}

// ---------------- causal GQA flash attention v2 ----------------
// grid: (qtile=32, hq=32, b=4); block 256 (4 waves x 16 q-rows), KBLK=64.
// Double-buffered K/V (one barrier/tile), XOR-swizzled LDS (linear 128B rows,
// slot ^= row&7), K staged via global_load_lds with pre-swizzled global source,
// mask only on diagonal tile, SCALE folded into Q.
__global__ __launch_bounds__(256) void attn_kernel(
    const u16* __restrict__ Q, const u16* __restrict__ Kb,
    const u16* __restrict__ Vb, u16* __restrict__ O)
{
  constexpr float SCALE = 0.02209708691207961f; // 1/sqrt(2048)
  __shared__ u16 Kl[2][64 * 64];
  __shared__ u16 Vt[2][64 * 64];     // V transposed: [d][kpos], swizzled
  __shared__ u16 Pl[4][16 * 64];     // per-wave P tile [q][kpos], swizzled
  const int qt = blockIdx.x, hq = blockIdx.y, b = blockIdx.z;
  const int kvh = hq >> 2;           // G = 4
  const int tid = threadIdx.x, lane = tid & 63, w = tid >> 6;
  const int g = lane >> 4, qn = lane & 15;
  const int sw = qn & 7;             // read-side swizzle key
  const int q_g = qt * 64 + w * 16 + qn;

  // Q fragment, scale folded in
  const u16* qrow = Q + ((size_t)(b * 2048 + q_g) * 2048 + hq * 64);
  bf16x8 qf[2];
  qf[0] = *reinterpret_cast<const bf16x8*>(qrow + g * 8);
  qf[1] = *reinterpret_cast<const bf16x8*>(qrow + g * 8 + 32);
  #pragma unroll
  for (int i = 0; i < 2; ++i)
    #pragma unroll
    for (int j = 0; j < 8; ++j)
      qf[i][j] = (short)f2bf(bf2f((u16)qf[i][j]) * SCALE);

  // diagonal-tile mask bits (kt==qt, cf==w): mask iff g*4+r > qn
  bool dmask[4];
  #pragma unroll
  for (int r = 0; r < 4; ++r) dmask[r] = (g * 4 + r) > qn;

  float m = -1e30f, l = 0.f;
  f32x4 oa[4];
  #pragma unroll
  for (int i = 0; i < 4; ++i) oa[i] = (f32x4){0.f, 0.f, 0.f, 0.f};

  const u16* Kbase = Kb + ((size_t)b * 2048 * 512 + kvh * 64);
  const u16* Vbase = Vb + ((size_t)b * 2048 * 512 + kvh * 64);
  const int nkt = qt + 1;
  const int lr = lane >> 3, lc = lane & 7;
  const int csw = lc ^ (lr & 7);     // pre-swizzled source slot for K staging

  // ---- prologue: stage tile 0 into buffer 0
  #pragma unroll
  for (int i = 0; i < 2; ++i) {
    int r0 = w * 16 + i * 8;
    GLOAD_LDS16(Kbase + (size_t)(r0 + lr) * 512 + csw * 8, &Kl[0][r0 * 64]);
  }
  #pragma unroll
  for (int i = 0; i < 2; ++i) {
    int rc = w + 4 * i;
    uint4 pk; u16* t = (u16*)&pk;
    #pragma unroll
    for (int j = 0; j < 8; ++j)
      t[j] = Vbase[(size_t)(rc * 8 + j) * 512 + lane];
    int slot = rc ^ (lane & 7);
    *reinterpret_cast<uint4*>(&Vt[0][lane * 64 + slot * 8]) = pk;
  }
  __syncthreads();

  int cur = 0;
  for (int kt = 0; kt < nkt; ++kt) {
    const bool haveNext = (kt + 1 < nkt);
    const bool last = (kt == nkt - 1);
    uint4 vr[2];
    if (haveNext) {
      // issue next K tile (async, lands in cur^1 before next barrier)
      #pragma unroll
      for (int i = 0; i < 2; ++i) {
        int r0 = w * 16 + i * 8;
        GLOAD_LDS16(Kbase + (size_t)((kt + 1) * 64 + r0 + lr) * 512 + csw * 8,
                    &Kl[cur ^ 1][r0 * 64]);
      }
      // issue next V gathers into regs (write to LDS after softmax)
      #pragma unroll
      for (int i = 0; i < 2; ++i) {
        int rc = w + 4 * i;
        u16* t = (u16*)&vr[i];
        #pragma unroll
        for (int j = 0; j < 8; ++j)
          t[j] = Vbase[(size_t)((kt + 1) * 64 + rc * 8 + j) * 512 + lane];
      }
    }

    // --- QK^T (S^T = K * Q^T): D row = kpos_local, col = q
    const u16* Kc = Kl[cur];
    f32x4 st[4];
    #pragma unroll
    for (int cf = 0; cf < 4; ++cf) st[cf] = (f32x4){0.f, 0.f, 0.f, 0.f};
    #pragma unroll
    for (int cf = 0; cf < 4; ++cf) {
      if (last && cf > w) continue;          // fully-masked fragment: skip
      #pragma unroll
      for (int ks = 0; ks < 2; ++ks) {
        int slot = (g + 4 * ks) ^ sw;
        bf16x8 kf = *reinterpret_cast<const bf16x8*>(Kc + (cf * 16 + qn) * 64 + slot * 8);
        st[cf] = MFMA_BF16(kf, qf[ks], st[cf]);
      }
    }

    // --- online softmax
    float pv[16];
    float tmax = -1e30f;
    #pragma unroll
    for (int cf = 0; cf < 4; ++cf) {
      if (last && cf > w) {
        #pragma unroll
        for (int r = 0; r < 4; ++r) pv[cf * 4 + r] = 0.f;   // zero P
      } else if (last && cf == w) {
        #pragma unroll
        for (int r = 0; r < 4; ++r) {
          float s = dmask[r] ? -1e30f : st[cf][r];
          pv[cf * 4 + r] = s; tmax = fmaxf(tmax, s);
        }
      } else {
        #pragma unroll
        for (int r = 0; r < 4; ++r) {
          float s = st[cf][r];
          pv[cf * 4 + r] = s; tmax = fmaxf(tmax, s);
        }
      }
    }
    tmax = fmaxf(tmax, __shfl_xor(tmax, 16));
    tmax = fmaxf(tmax, __shfl_xor(tmax, 32));
    float mnew = fmaxf(m, tmax);
    float fac = __expf(m - mnew);
    float lsum = 0.f;
    #pragma unroll
    for (int cf = 0; cf < 4; ++cf) {
      if (last && cf > w) continue;          // pv already zero
      #pragma unroll
      for (int r = 0; r < 4; ++r) {
        float p = __expf(pv[cf * 4 + r] - mnew);
        pv[cf * 4 + r] = p; lsum += p;
      }
    }
    lsum += __shfl_xor(lsum, 16);
    lsum += __shfl_xor(lsum, 32);
    l = l * fac + lsum;
    m = mnew;
    #pragma unroll
    for (int r = 0; r < 4; ++r) {
      float fr = __shfl(fac, (lane & 48) | (g * 4 + r));
      #pragma unroll
      for (int df = 0; df < 4; ++df) oa[df][r] *= fr;
    }

    // --- write P (b64 per fragment, swizzled); per-wave tile, no barrier needed
    u16* Pw = Pl[w];
    #pragma unroll
    for (int cf = 0; cf < 4; ++cf) {
      uint32_t lo = (uint32_t)f2bf(pv[cf * 4 + 0]) | ((uint32_t)f2bf(pv[cf * 4 + 1]) << 16);
      uint32_t hi = (uint32_t)f2bf(pv[cf * 4 + 2]) | ((uint32_t)f2bf(pv[cf * 4 + 3]) << 16);
      int slot = (2 * cf + (g >> 1)) ^ sw;
      uint2 u2; u2.x = lo; u2.y = hi;
      *reinterpret_cast<uint2*>(Pw + qn * 64 + slot * 8 + (g & 1) * 4) = u2;
    }

    // --- next V tile LDS write (loads issued earlier; hides under softmax)
    if (haveNext) {
      #pragma unroll
      for (int i = 0; i < 2; ++i) {
        int rc = w + 4 * i;
        int slot = rc ^ (lane & 7);
        *reinterpret_cast<uint4*>(&Vt[cur ^ 1][lane * 64 + slot * 8]) = vr[i];
      }
    }

    // --- PV: O += P * V
    const u16* Vc = Vt[cur];
    #pragma unroll
    for (int ks = 0; ks < 2; ++ks) {
      int slotp = (g + 4 * ks) ^ sw;
      bf16x8 pa = *reinterpret_cast<const bf16x8*>(Pw + qn * 64 + slotp * 8);
      #pragma unroll
      for (int df = 0; df < 4; ++df) {
        bf16x8 vf = *reinterpret_cast<const bf16x8*>(Vc + (df * 16 + qn) * 64 + slotp * 8);
        oa[df] = MFMA_BF16(pa, vf, oa[df]);
      }
    }
    __syncthreads();
    cur ^= 1;
  }

  // epilogue: normalize rows, store O bf16 at [b][q][hq*64+d]
  #pragma unroll
  for (int r = 0; r < 4; ++r) {
    float lrv = __shfl(l, (lane & 48) | (g * 4 + r));
    float inv = 1.f / lrv;
    int row_g = qt * 64 + w * 16 + g * 4 + r;
    u16* orow = O + ((size_t)(b * 2048 + row_g) * 2048 + hq * 64);
    #pragma unroll
    for (int df = 0; df < 4; ++df)
      orow[df * 16 + qn] = f2bf(oa[df][r] * inv);
  }
}

// ---------------- launch ----------------
// Workspace layout (lifetime-aliased, peak 96,468,992 B):
//   [0,        33.5M)  x_bf (dead after QKV GEMMs) -> reused as Ob
//   [33.5M,    67.1M)  Qb
//   [67.1M,    75.5M)  Kb
//   [75.5M,    83.9M)  Vb
//   [83.9M,    92.3M)  Wbuf: wq_bf then wo_bf
//   [92.3M,    94.4M)  wk_bf
//   [94.4M,    96.5M)  wv_bf
extern "C" void kernel_launch(void* const* d_in, const int* in_sizes, int n_in,
                              void* d_out, int out_size, void* d_ws, size_t ws_size,
                              hipStream_t stream) {
  const float* x    = (const float*)d_in[0];
  const float* fc   = (const float*)d_in[1];
  const float* fs   = (const float*)d_in[2];
  const float* wq_w = (const float*)d_in[3];
  const float* wq_b = (const float*)d_in[4];
  const float* wk_w = (const float*)d_in[5];
  const float* wk_b = (const float*)d_in[6];
  const float* wv_w = (const float*)d_in[7];
  const float* wv_b = (const float*)d_in[8];
  const float* wo_w = (const float*)d_in[9];
  const float* wo_b = (const float*)d_in[10];
  float* out = (float*)d_out;
  char* ws = (char*)d_ws;

  const size_t NEEDED = 96468992;
  if (ws_size < NEEDED) return;

  u16* x_bf  = (u16*)(ws);
  u16* Qb    = (u16*)(ws + 33554432);
  u16* Kb    = (u16*)(ws + 67108864);
  u16* Vb    = (u16*)(ws + 75497472);
  u16* Wbuf  = (u16*)(ws + 83886080);
  u16* wk_bf = (u16*)(ws + 92274688);
  u16* wv_bf = (u16*)(ws + 94371840);
  u16* Ob    = x_bf;                       // alias (x_bf dead after QKV GEMMs)

  // fp32 -> bf16
  cvt_kernel<<<16384, 256, 0, stream>>>(x,    x_bf, 4194304);
  cvt_kernel<<< 4096, 256, 0, stream>>>(wq_w, Wbuf, 1048576);
  cvt_kernel<<< 1024, 256, 0, stream>>>(wk_w, wk_bf, 262144);
  cvt_kernel<<< 1024, 256, 0, stream>>>(wv_w, wv_bf, 262144);

  // QKV projections
  gemm_bt<u16><<<dim3(16, 64), 256, 0, stream>>>(x_bf, Wbuf,  wq_b, Qb, 8192, 2048, 2048);
  gemm_bt<u16><<<dim3( 4, 64), 256, 0, stream>>>(x_bf, wk_bf, wk_b, Kb, 8192,  512, 2048);
  gemm_bt<u16><<<dim3( 4, 64), 256, 0, stream>>>(x_bf, wv_bf, wv_b, Vb, 8192,  512, 2048);

  // wo conversion into Wbuf (stream-serial: wq dead)
  cvt_kernel<<< 4096, 256, 0, stream>>>(wo_w, Wbuf, 1048576);

  // RoPE on Q and K
  rope_kernel<<<8192, 256, 0, stream>>>(Qb, fc, fs, 256, 2097152);
  rope_kernel<<<2048, 256, 0, stream>>>(Kb, fc, fs,  64,  524288);

  // attention
  attn_kernel<<<dim3(32, 32, 4), 256, 0, stream>>>(Qb, Kb, Vb, Ob);

  // output projection (fp32 out + bias)
  gemm_bt<float><<<dim3(16, 64), 256, 0, stream>>>(Ob, Wbuf, wo_b, out, 8192, 2048, 2048);
}

// Round 7
// 728.579 us; speedup vs baseline: 1.0745x; 1.0745x over previous
//
#include <hip/hip_runtime.h>
#include <hip/hip_bf16.h>
#include <stdint.h>

typedef unsigned short u16;
typedef __attribute__((ext_vector_type(8))) short bf16x8;
typedef __attribute__((ext_vector_type(4))) float f32x4;

#define MFMA_BF16(a,b,c) __builtin_amdgcn_mfma_f32_16x16x32_bf16((a),(b),(c),0,0,0)

// async global->LDS, 16B per lane; LDS dest = wave-uniform base + lane*16
#define GLOAD_LDS16(g, l) \
  __builtin_amdgcn_global_load_lds((const __attribute__((address_space(1))) void*)(g), \
                                   (__attribute__((address_space(3))) void*)(l), 16, 0, 0)

__device__ inline u16 f2bf(float f) {
  return __builtin_bit_cast(u16, __float2bfloat16(f));
}
__device__ inline float bf2f(u16 h) {
  uint32_t u = ((uint32_t)h) << 16;
  return __builtin_bit_cast(float, u);
}
__device__ inline float exp2a(float x) {   // v_exp_f32 computes 2^x directly
  float r; asm("v_exp_f32 %0, %1" : "=v"(r) : "v"(x)); return r;
}

// ---------------- fp32 -> bf16 conversion ----------------
__global__ __launch_bounds__(256) void cvt_kernel(const float* __restrict__ src,
                                                  u16* __restrict__ dst, int n4) {
  int i = blockIdx.x * 256 + threadIdx.x;
  if (i >= n4) return;
  float4 v = reinterpret_cast<const float4*>(src)[i];
  uint2 o;
  o.x = (uint32_t)f2bf(v.x) | ((uint32_t)f2bf(v.y) << 16);
  o.y = (uint32_t)f2bf(v.z) | ((uint32_t)f2bf(v.w) << 16);
  reinterpret_cast<uint2*>(dst)[i] = o;
}

// ---------------- GEMM (m97 structure): C = A * B^T + bias ----------------
template<typename OutT>
__global__ __launch_bounds__(256) void gemm_bt(
    const u16* __restrict__ A, const u16* __restrict__ B,
    const float* __restrict__ bias, OutT* __restrict__ C,
    int M, int N, int K)
{
  __shared__ u16 As[128 * 64];
  __shared__ u16 Bs[128 * 64];
  const int bm = blockIdx.y, bn = blockIdx.x;
  const int tid = threadIdx.x;
  const int lane = tid & 63;
  const int wv = tid >> 6;
  const int wm = wv >> 1, wn = wv & 1;
  const int g = lane >> 4, qn = lane & 15;

  f32x4 acc[4][4];
  #pragma unroll
  for (int i = 0; i < 4; ++i)
    #pragma unroll
    for (int j = 0; j < 4; ++j) acc[i][j] = (f32x4){0.f, 0.f, 0.f, 0.f};

  const u16* Ab = A + (size_t)bm * 128 * K;
  const u16* Bb = B + (size_t)bn * 128 * K;
  const int lr = lane >> 3, lc = lane & 7;

  for (int kt = 0; kt < K; kt += 64) {
    __syncthreads();
    #pragma unroll
    for (int i = 0; i < 4; ++i) {
      int r0 = wv * 32 + i * 8;
      size_t goff = (size_t)(r0 + lr) * K + kt + lc * 8;
      GLOAD_LDS16(Ab + goff, As + r0 * 64);
      GLOAD_LDS16(Bb + goff, Bs + r0 * 64);
    }
    __syncthreads();
    #pragma unroll
    for (int ks = 0; ks < 2; ++ks) {
      bf16x8 af[4], bfr[4];
      #pragma unroll
      for (int mi = 0; mi < 4; ++mi)
        af[mi] = *reinterpret_cast<const bf16x8*>(As + (wm * 64 + mi * 16 + qn) * 64 + g * 8 + ks * 32);
      #pragma unroll
      for (int ni = 0; ni < 4; ++ni)
        bfr[ni] = *reinterpret_cast<const bf16x8*>(Bs + (wn * 64 + ni * 16 + qn) * 64 + g * 8 + ks * 32);
      #pragma unroll
      for (int mi = 0; mi < 4; ++mi)
        #pragma unroll
        for (int ni = 0; ni < 4; ++ni)
          acc[mi][ni] = MFMA_BF16(af[mi], bfr[ni], acc[mi][ni]);
    }
  }
  #pragma unroll
  for (int ni = 0; ni < 4; ++ni) {
    int col = bn * 128 + wn * 64 + ni * 16 + qn;
    float bs = bias[col];
    #pragma unroll
    for (int mi = 0; mi < 4; ++mi) {
      #pragma unroll
      for (int r = 0; r < 4; ++r) {
        int row = bm * 128 + wm * 64 + mi * 16 + g * 4 + r;
        float v = acc[mi][ni][r] + bs;
        if constexpr (sizeof(OutT) == 2) C[(size_t)row * N + col] = (OutT)f2bf(v);
        else                             C[(size_t)row * N + col] = v;
      }
    }
  }
}

// ---------------- RoPE (in-place, K only) ----------------
__global__ __launch_bounds__(256) void rope_kernel(
    u16* __restrict__ T, const float* __restrict__ cosT, const float* __restrict__ sinT,
    int heads8, int n8)
{
  int i = blockIdx.x * 256 + threadIdx.x;
  if (i >= n8) return;
  int tok = i / heads8;
  int r = i - tok * heads8;
  int d0 = (r & 7) * 8;
  int s = tok & 2047;
  uint4 v = reinterpret_cast<uint4*>(T)[i];
  u16* e = reinterpret_cast<u16*>(&v);
  float4 c = *reinterpret_cast<const float4*>(cosT + s * 32 + d0 / 2);
  float4 sn = *reinterpret_cast<const float4*>(sinT + s * 32 + d0 / 2);
  float cc[4] = {c.x, c.y, c.z, c.w}, ss[4] = {sn.x, sn.y, sn.z, sn.w};
  #pragma unroll
  for (int j = 0; j < 4; ++j) {
    float tr = bf2f(e[2 * j]), ti = bf2f(e[2 * j + 1]);
    e[2 * j]     = f2bf(tr * cc[j] - ti * ss[j]);
    e[2 * j + 1] = f2bf(tr * ss[j] + ti * cc[j]);
  }
  reinterpret_cast<uint4*>(T)[i] = v;
}

// ---------------- causal GQA flash attention v3 ----------------
// grid (qtile=16, hq=32, b=4); block 256 = 4 waves; wave handles 32 q-rows
// (2 fragments of 16). KVBLK=64, dbuf K/V, XOR-swizzled LDS, RoPE folded
// into Q load, exp2-domain softmax, hoisted staging pointers.
__global__ __launch_bounds__(256, 3) void attn_kernel(
    const u16* __restrict__ Q, const u16* __restrict__ Kb,
    const u16* __restrict__ Vb, const float* __restrict__ cosT,
    const float* __restrict__ sinT, u16* __restrict__ O)
{
  // 1/sqrt(2048) * log2(e): softmax computed in base-2 domain
  constexpr float SCALE2 = 0.02209708691207961f * 1.4426950408889634f;
  __shared__ u16 Kl[2][64 * 64];
  __shared__ u16 Vt[2][64 * 64];     // V^T [d][kpos], swizzled
  __shared__ u16 Pl[4][32 * 64];     // per-wave P [q][kpos], swizzled
  const int qt = blockIdx.x, hq = blockIdx.y, b = blockIdx.z;
  const int kvh = hq >> 2;
  const int tid = threadIdx.x, lane = tid & 63, w = tid >> 6;
  const int g = lane >> 4, qn = lane & 15;
  const int sw = qn & 7;

  // ---- Q load + RoPE + scale fold (once)
  bf16x8 qf[2][2];
  #pragma unroll
  for (int a = 0; a < 2; ++a) {
    int qg = qt * 128 + w * 32 + a * 16 + qn;
    const u16* qrow = Q + ((size_t)(b * 2048 + qg) * 2048 + hq * 64);
    #pragma unroll
    for (int ks = 0; ks < 2; ++ks) {
      bf16x8 raw = *reinterpret_cast<const bf16x8*>(qrow + ks * 32 + g * 8);
      float4 c4 = *reinterpret_cast<const float4*>(cosT + qg * 32 + ks * 16 + g * 4);
      float4 s4 = *reinterpret_cast<const float4*>(sinT + qg * 32 + ks * 16 + g * 4);
      float cc[4] = {c4.x, c4.y, c4.z, c4.w}, ssv[4] = {s4.x, s4.y, s4.z, s4.w};
      bf16x8 o;
      #pragma unroll
      for (int t = 0; t < 4; ++t) {
        float tr = bf2f((u16)raw[2 * t]), ti = bf2f((u16)raw[2 * t + 1]);
        o[2 * t]     = (short)f2bf((tr * cc[t] - ti * ssv[t]) * SCALE2);
        o[2 * t + 1] = (short)f2bf((tr * ssv[t] + ti * cc[t]) * SCALE2);
      }
      qf[a][ks] = o;
    }
  }

  float m[2] = {-3.0e38f, -3.0e38f}, l[2] = {0.f, 0.f};
  f32x4 oa[2][4];
  #pragma unroll
  for (int a = 0; a < 2; ++a)
    #pragma unroll
    for (int df = 0; df < 4; ++df) oa[a][df] = (f32x4){0.f, 0.f, 0.f, 0.f};

  const u16* Kbase = Kb + ((size_t)b * 2048 * 512 + kvh * 64);
  const u16* Vbase = Vb + ((size_t)b * 2048 * 512 + kvh * 64);
  const int lr = lane >> 3, lc = lane & 7;
  const int csw = lc ^ (lr & 7);

  // running pointers (advance 64*512 elems per tile)
  const u16* kp0 = Kbase + (size_t)(w * 16 + lr) * 512 + csw * 8;
  const u16* kp1 = kp0 + 8 * 512;
  const u16* vpA[2]; const u16* vpB[2];
  #pragma unroll
  for (int i = 0; i < 2; ++i) {
    int rc = w + 4 * i;
    vpA[i] = Vbase + (size_t)(rc * 8) * 512 + lane;
    vpB[i] = vpA[i] + 4 * 512;
  }

  // ---- prologue: stage tile 0
  GLOAD_LDS16(kp0, &Kl[0][(w * 16) * 64]);
  GLOAD_LDS16(kp1, &Kl[0][(w * 16 + 8) * 64]);
  kp0 += 32768; kp1 += 32768;
  #pragma unroll
  for (int i = 0; i < 2; ++i) {
    int rc = w + 4 * i;
    uint4 pk; u16* t = (u16*)&pk;
    #pragma unroll
    for (int j = 0; j < 4; ++j) { t[j] = vpA[i][j * 512]; t[4 + j] = vpB[i][j * 512]; }
    vpA[i] += 32768; vpB[i] += 32768;
    int slot = rc ^ (lane & 7);
    *reinterpret_cast<uint4*>(&Vt[0][lane * 64 + slot * 8]) = pk;
  }
  __syncthreads();

  const int nkt = 2 * qt + 2;
  int cur = 0;
  for (int kt = 0; kt < nkt; ++kt) {
    const bool haveNext = (kt + 1 < nkt);
    uint4 vr0, vr1;
    if (haveNext) {
      GLOAD_LDS16(kp0, &Kl[cur ^ 1][(w * 16) * 64]);
      GLOAD_LDS16(kp1, &Kl[cur ^ 1][(w * 16 + 8) * 64]);
      kp0 += 32768; kp1 += 32768;
      u16* t0 = (u16*)&vr0; u16* t1 = (u16*)&vr1;
      #pragma unroll
      for (int j = 0; j < 4; ++j) { t0[j] = vpA[0][j * 512]; t0[4 + j] = vpB[0][j * 512]; }
      vpA[0] += 32768; vpB[0] += 32768;
      #pragma unroll
      for (int j = 0; j < 4; ++j) { t1[j] = vpA[1][j * 512]; t1[4 + j] = vpB[1][j * 512]; }
      vpA[1] += 32768; vpB[1] += 32768;
    }

    // --- QK^T (swapped: S^T = K*Q^T). dd = k-frag base minus q-frag base.
    const u16* Kc = Kl[cur];
    const int ddb = kt * 64 - (qt * 128 + w * 32);   // dd for a=0, cf=0
    f32x4 st[2][4];
    #pragma unroll
    for (int a = 0; a < 2; ++a)
      #pragma unroll
      for (int cf = 0; cf < 4; ++cf) st[a][cf] = (f32x4){0.f, 0.f, 0.f, 0.f};

    #pragma unroll
    for (int cf = 0; cf < 4; ++cf) {
      int dd0 = ddb + cf * 16;
      int dd1 = dd0 - 16;
      if (dd1 >= 16) continue;                        // dead for both frags
      bf16x8 kf0 = *reinterpret_cast<const bf16x8*>(Kc + (cf * 16 + qn) * 64 + ((g) ^ sw) * 8);
      bf16x8 kf1 = *reinterpret_cast<const bf16x8*>(Kc + (cf * 16 + qn) * 64 + ((g + 4) ^ sw) * 8);
      if (dd0 < 16) {
        st[0][cf] = MFMA_BF16(kf0, qf[0][0], st[0][cf]);
        st[0][cf] = MFMA_BF16(kf1, qf[0][1], st[0][cf]);
      }
      st[1][cf] = MFMA_BF16(kf0, qf[1][0], st[1][cf]);
      st[1][cf] = MFMA_BF16(kf1, qf[1][1], st[1][cf]);
    }

    // --- online softmax (base-2), per q-frag
    float fac[2]; bool doP[2];
    #pragma unroll
    for (int a = 0; a < 2; ++a) {
      int dda = ddb - a * 16;
      doP[a] = (dda < 16);
      fac[a] = 1.f;
      if (!doP[a]) continue;
      float tmax = -3.0e38f;
      #pragma unroll
      for (int cf = 0; cf < 4; ++cf) {
        int dd = dda + cf * 16;
        if (dd >= 16) continue;                       // skipped frag (st=0, P=0)
        if (dd > -16) {                               // diagonal frag: per-lane mask
          int thr = qn - dd;
          #pragma unroll
          for (int r = 0; r < 4; ++r) {
            float s = (g * 4 + r > thr) ? -3.0e38f : st[a][cf][r];
            st[a][cf][r] = s;
            tmax = fmaxf(tmax, s);
          }
        } else {
          #pragma unroll
          for (int r = 0; r < 4; ++r) tmax = fmaxf(tmax, st[a][cf][r]);
        }
      }
      tmax = fmaxf(tmax, __shfl_xor(tmax, 16));
      tmax = fmaxf(tmax, __shfl_xor(tmax, 32));
      float mnew = fmaxf(m[a], tmax);
      fac[a] = exp2a(m[a] - mnew);
      float lsum = 0.f;
      #pragma unroll
      for (int cf = 0; cf < 4; ++cf) {
        int dd = dda + cf * 16;
        if (dd >= 16) continue;
        #pragma unroll
        for (int r = 0; r < 4; ++r) {
          float p = exp2a(st[a][cf][r] - mnew);
          st[a][cf][r] = p;
          lsum += p;
        }
      }
      lsum += __shfl_xor(lsum, 16);
      lsum += __shfl_xor(lsum, 32);
      l[a] = l[a] * fac[a] + lsum;
      m[a] = mnew;
      #pragma unroll
      for (int r = 0; r < 4; ++r) {
        float fr = __shfl(fac[a], (lane & 48) | (g * 4 + r));
        #pragma unroll
        for (int df = 0; df < 4; ++df) oa[a][df][r] *= fr;
      }
    }

    // --- write P tiles (bf16, swizzled); per-wave region, no barrier needed
    u16* Pw = Pl[w];
    #pragma unroll
    for (int a = 0; a < 2; ++a) {
      if (!doP[a]) continue;
      #pragma unroll
      for (int cf = 0; cf < 4; ++cf) {
        uint32_t lo = (uint32_t)f2bf(st[a][cf][0]) | ((uint32_t)f2bf(st[a][cf][1]) << 16);
        uint32_t hi = (uint32_t)f2bf(st[a][cf][2]) | ((uint32_t)f2bf(st[a][cf][3]) << 16);
        int slot = (2 * cf + (g >> 1)) ^ sw;
        uint2 u2; u2.x = lo; u2.y = hi;
        *reinterpret_cast<uint2*>(Pw + (a * 16 + qn) * 64 + slot * 8 + (g & 1) * 4) = u2;
      }
    }

    // --- next V tile LDS write (loads issued before QK; hides under softmax)
    if (haveNext) {
      int slot0 = w ^ (lane & 7);
      int slot1 = (w + 4) ^ (lane & 7);
      *reinterpret_cast<uint4*>(&Vt[cur ^ 1][lane * 64 + slot0 * 8]) = vr0;
      *reinterpret_cast<uint4*>(&Vt[cur ^ 1][lane * 64 + slot1 * 8]) = vr1;
    }

    // --- PV: O += P * V  (V fragments shared across both q-frags)
    const u16* Vc = Vt[cur];
    #pragma unroll
    for (int ks = 0; ks < 2; ++ks) {
      int slotv = (g + 4 * ks) ^ sw;
      bf16x8 vf[4];
      #pragma unroll
      for (int df = 0; df < 4; ++df)
        vf[df] = *reinterpret_cast<const bf16x8*>(Vc + (df * 16 + qn) * 64 + slotv * 8);
      #pragma unroll
      for (int a = 0; a < 2; ++a) {
        if (!doP[a]) continue;
        bf16x8 pa = *reinterpret_cast<const bf16x8*>(Pw + (a * 16 + qn) * 64 + slotv * 8);
        #pragma unroll
        for (int df = 0; df < 4; ++df)
          oa[a][df] = MFMA_BF16(pa, vf[df], oa[a][df]);
      }
    }
    __syncthreads();
    cur ^= 1;
  }

  // ---- epilogue: normalize, store bf16 O at [b][q][hq*64+d]
  #pragma unroll
  for (int a = 0; a < 2; ++a) {
    #pragma unroll
    for (int r = 0; r < 4; ++r) {
      float lrv = __shfl(l[a], (lane & 48) | (g * 4 + r));
      float inv = 1.f / lrv;
      int row_g = qt * 128 + w * 32 + a * 16 + g * 4 + r;
      u16* orow = O + ((size_t)(b * 2048 + row_g) * 2048 + hq * 64);
      #pragma unroll
      for (int df = 0; df < 4; ++df)
        orow[df * 16 + qn] = f2bf(oa[a][df][r] * inv);
    }
  }
}

// ---------------- launch ----------------
// Workspace layout (lifetime-aliased, peak 96,468,992 B):
//   [0,33.5M) x_bf -> later Ob | [33.5,67.1) Qb | [67.1,75.5) Kb
//   [75.5,83.9) Vb | [83.9,92.3) Wbuf (wq then wo) | [92.3,94.4) wk | [94.4,96.5) wv
extern "C" void kernel_launch(void* const* d_in, const int* in_sizes, int n_in,
                              void* d_out, int out_size, void* d_ws, size_t ws_size,
                              hipStream_t stream) {
  const float* x    = (const float*)d_in[0];
  const float* fc   = (const float*)d_in[1];
  const float* fs   = (const float*)d_in[2];
  const float* wq_w = (const float*)d_in[3];
  const float* wq_b = (const float*)d_in[4];
  const float* wk_w = (const float*)d_in[5];
  const float* wk_b = (const float*)d_in[6];
  const float* wv_w = (const float*)d_in[7];
  const float* wv_b = (const float*)d_in[8];
  const float* wo_w = (const float*)d_in[9];
  const float* wo_b = (const float*)d_in[10];
  float* out = (float*)d_out;
  char* ws = (char*)d_ws;

  const size_t NEEDED = 96468992;
  if (ws_size < NEEDED) return;

  u16* x_bf  = (u16*)(ws);
  u16* Qb    = (u16*)(ws + 33554432);
  u16* Kb    = (u16*)(ws + 67108864);
  u16* Vb    = (u16*)(ws + 75497472);
  u16* Wbuf  = (u16*)(ws + 83886080);
  u16* wk_bf = (u16*)(ws + 92274688);
  u16* wv_bf = (u16*)(ws + 94371840);
  u16* Ob    = x_bf;                       // alias (x_bf dead after QKV GEMMs)

  // fp32 -> bf16
  cvt_kernel<<<16384, 256, 0, stream>>>(x,    x_bf, 4194304);
  cvt_kernel<<< 4096, 256, 0, stream>>>(wq_w, Wbuf, 1048576);
  cvt_kernel<<< 1024, 256, 0, stream>>>(wk_w, wk_bf, 262144);
  cvt_kernel<<< 1024, 256, 0, stream>>>(wv_w, wv_bf, 262144);

  // QKV projections
  gemm_bt<u16><<<dim3(16, 64), 256, 0, stream>>>(x_bf, Wbuf,  wq_b, Qb, 8192, 2048, 2048);
  gemm_bt<u16><<<dim3( 4, 64), 256, 0, stream>>>(x_bf, wk_bf, wk_b, Kb, 8192,  512, 2048);
  gemm_bt<u16><<<dim3( 4, 64), 256, 0, stream>>>(x_bf, wv_bf, wv_b, Vb, 8192,  512, 2048);

  // wo conversion into Wbuf (stream-serial: wq dead)
  cvt_kernel<<< 4096, 256, 0, stream>>>(wo_w, Wbuf, 1048576);

  // RoPE on K only (Q RoPE fused into attn)
  rope_kernel<<<2048, 256, 0, stream>>>(Kb, fc, fs, 64, 524288);

  // attention (RoPE(Q) + softmax fused)
  attn_kernel<<<dim3(16, 32, 4), 256, 0, stream>>>(Qb, Kb, Vb, fc, fs, Ob);

  // output projection (fp32 out + bias)
  gemm_bt<float><<<dim3(16, 64), 256, 0, stream>>>(Ob, Wbuf, wo_b, out, 8192, 2048, 2048);
}